// Round 11
// baseline (262.686 us; speedup 1.0000x reference)
//
#include <hip/hip_runtime.h>
#include <math.h>

// Causal depthwise conv1d K=4 + SiLU. x (B=4, T=4096, C=2048) fp32, kernel (4, C) fp32.
// y[b,t,c] = silu( sum_j k[j,c] * x[b,t-j,c] ), zero-padded; next_cache = x[:, T-3:, :].
//
// R12 post-mortem: 3-deep counted-vmcnt DMA pipeline (verified live: LDS=64K, VGPR=88)
//   = 81us = R10's full-drain = R11's 1-deep. Outstanding-bytes model falsified; ten
//   structure-invariant rounds -> wall is upstream of everything varied so far.
// R13: self-instrumenting round. Dispatch 1 primes: pure-read of x at max TLP
//   (fill-regime: ~45 VGPR, 32 waves/CU, ballast-forced 8-deep batches) -> in-session
//   pure-READ benchmark + makes x LLC-resident (134MB < 256MB, evicts poison).
//   Dispatch 2: best-known conv (R5 verbatim) now reading LLC-warm x -> HBM sees
//   writes only. Distinguishes H-turnaround (mixed-stream penalty; conv -> 30-45us)
//   from H-readslow (prime itself ~45us+) from store-path wall (prime fast, conv flat).

#define B_   4
#define T_   4096
#define C_   2048
#define K_   4
#define C4_  (C_ / 4)   // 512 float4 groups per row
#define TG_  4          // t rows per thread (conv)
#define NT_  (T_ / TG_) // 1024 t-groups

typedef float f4 __attribute__((ext_vector_type(4)));

__device__ __forceinline__ float silu_f(float v) {
    return v * __builtin_amdgcn_rcpf(1.f + __expf(-v));
}

// ---------- Dispatch 1: pure-read prime (in-session read benchmark) ----------
// 4096 blocks x 256 thr = 1,048,576 threads; 8,388,608 f4 total -> 8 f4/thread,
// stride-partitioned. 8 independent loads batched, liveness-ballast forces all 8
// destinations live (R7 mechanism) -> 8 KB/wave in flight; ~45 VGPR -> 32 waves/CU.
__global__ __launch_bounds__(256, 8) void prime_x_kernel(const f4* __restrict__ x)
{
    const size_t n      = (size_t)B_ * T_ * C4_;        // 8,388,608
    const size_t stride = (size_t)4096 * 256;           // 1,048,576
    const size_t p      = (size_t)blockIdx.x * 256 + threadIdx.x;

    f4 v0 = x[p + 0 * stride];
    f4 v1 = x[p + 1 * stride];
    f4 v2 = x[p + 2 * stride];
    f4 v3 = x[p + 3 * stride];
    f4 v4 = x[p + 4 * stride];
    f4 v5 = x[p + 5 * stride];
    f4 v6 = x[p + 6 * stride];
    f4 v7 = x[p + 7 * stride];
    (void)n;

    // Ballast: loads are live, nothing is stored, nothing can be DCE'd.
    asm volatile(""
        :
        : "v"(v0), "v"(v1), "v"(v2), "v"(v3),
          "v"(v4), "v"(v5), "v"(v6), "v"(v7));
}

// ---------- Dispatch 2: conv, R5-verbatim (best known, ~74.7us standalone) ----------
__global__ __launch_bounds__(256, 4) void dwconv_silu_kernel(
    const f4* __restrict__ x,      // [B, T, C4]
    const f4* __restrict__ kern,   // [K, C4]
    f4* __restrict__ y,            // [B, T, C4]
    f4* __restrict__ cache)        // [B, K-1, C4]
{
    const int j  = blockIdx.x * 256 + threadIdx.x;
    const int c4 = j & (C4_ - 1);
    const int tg = (j >> 9) & (NT_ - 1);
    const int b  = j >> 19;            // 9 bits c4 + 10 bits tg
    const int t0 = tg * TG_;

    const f4* xp = x + (((size_t)b * T_ + t0) * C4_ + c4);

    const f4 k0 = kern[0 * C4_ + c4];
    const f4 k1 = kern[1 * C4_ + c4];
    const f4 k2 = kern[2 * C4_ + c4];
    const f4 k3 = kern[3 * C4_ + c4];

    f4 m3, m2, m1;
    if (t0 == 0) {
        m3 = m2 = m1 = (f4){0.f, 0.f, 0.f, 0.f};
    } else {
        m3 = xp[-3 * C4_];
        m2 = xp[-2 * C4_];
        m1 = xp[-1 * C4_];
    }
    const f4 a0 = xp[0 * C4_];
    const f4 a1 = xp[1 * C4_];
    const f4 a2 = xp[2 * C4_];
    const f4 a3 = xp[3 * C4_];

    __builtin_amdgcn_sched_barrier(0);

#define CONV1(r, a, w1, w2, w3)                                              \
    r.x = fmaf(k0.x, a.x, fmaf(k1.x, w1.x, fmaf(k2.x, w2.x, k3.x * w3.x)));  \
    r.y = fmaf(k0.y, a.y, fmaf(k1.y, w1.y, fmaf(k2.y, w2.y, k3.y * w3.y)));  \
    r.z = fmaf(k0.z, a.z, fmaf(k1.z, w1.z, fmaf(k2.z, w2.z, k3.z * w3.z)));  \
    r.w = fmaf(k0.w, a.w, fmaf(k1.w, w1.w, fmaf(k2.w, w2.w, k3.w * w3.w)));  \
    r.x = silu_f(r.x); r.y = silu_f(r.y); r.z = silu_f(r.z); r.w = silu_f(r.w);

    f4 r0, r1, r2, r3;
    CONV1(r0, a0, m1, m2, m3)
    CONV1(r1, a1, a0, m1, m2)
    CONV1(r2, a2, a1, a0, m1)
    CONV1(r3, a3, a2, a1, a0)
#undef CONV1

    f4* yp = y + (((size_t)b * T_ + t0) * C4_ + c4);
    yp[0 * C4_] = r0;
    yp[1 * C4_] = r1;
    yp[2 * C4_] = r2;
    yp[3 * C4_] = r3;

    if (tg == NT_ - 1) {
        f4* cb = cache + (size_t)b * (K_ - 1) * C4_ + c4;
        cb[0 * C4_] = a1;
        cb[1 * C4_] = a2;
        cb[2 * C4_] = a3;
    }
}

extern "C" void kernel_launch(void* const* d_in, const int* in_sizes, int n_in,
                              void* d_out, int out_size, void* d_ws, size_t ws_size,
                              hipStream_t stream)
{
    const f4* x    = (const f4*)d_in[0];
    const f4* kern = (const f4*)d_in[1];
    float*    out  = (float*)d_out;

    f4* y     = (f4*)out;
    f4* cache = (f4*)(out + (size_t)B_ * T_ * C_);

    // Dispatch 1: prime x into LLC (and benchmark the pure-read stream).
    prime_x_kernel<<<dim3(4096), dim3(256), 0, stream>>>(x);

    // Dispatch 2: conv with (ideally) LLC-warm x.
    const int total_threads = B_ * NT_ * C4_;          // 2,097,152
    dwconv_silu_kernel<<<dim3(total_threads / 256), dim3(256), 0, stream>>>(
        x, kern, y, cache);
}